// Round 3
// baseline (710.514 us; speedup 1.0000x reference)
//
#include <hip/hip_runtime.h>

typedef __attribute__((ext_vector_type(8))) short short8;
typedef __attribute__((ext_vector_type(16))) float f32x16;
typedef __attribute__((ext_vector_type(4))) unsigned short us4;

#define MFMA32(a,b,c) __builtin_amdgcn_mfma_f32_32x32x16_bf16((a),(b),(c),0,0,0)

__device__ __forceinline__ unsigned short f2bf(float f) {
  union { float f; unsigned u; } v; v.f = f;
  return (unsigned short)((v.u + 0x7fffu + ((v.u >> 16) & 1u)) >> 16);
}
__device__ __forceinline__ float bf2f(unsigned short h) {
  union { unsigned u; float f; } v; v.u = ((unsigned)h) << 16;
  return v.f;
}
__device__ __forceinline__ f32x16 zero16() {
  f32x16 v;
  #pragma unroll
  for (int i = 0; i < 16; ++i) v[i] = 0.f;
  return v;
}

// ---------------- prep: weights -> bf16 fragment-major layouts --------------
// All B-fragments stored so that MFMA32 B operand is a contiguous 1KB load:
//   frag[unit][ks][lane*8+e] = W[k = ks*16 + (lane>>5)*8 + e][col = base + (lane&31)]
// wtcf: [29 taps][2 nhalf][12 ks][512]   (conv, K=192)
// w1f : [3 nt][20 ks][512]  cols 80..95 zero-padded (att1, K=320)
// w2f : [10 nt][6 ks][512]  k 80..95 zero-padded    (att2, K=96)
// wof : [10 nt][20 ks][512]                          (out,  K=320)
__global__ __launch_bounds__(256) void k_prep(
    const float* __restrict__ w1, const float* __restrict__ w2,
    const float* __restrict__ w3, const float* __restrict__ w4,
    const float* __restrict__ w5,
    const float* __restrict__ b1, const float* __restrict__ b2,
    const float* __restrict__ b3, const float* __restrict__ b4,
    const float* __restrict__ b5,
    const float* __restrict__ wa1, const float* __restrict__ wa2,
    const float* __restrict__ wo,
    unsigned short* __restrict__ wtcf, unsigned short* __restrict__ w1f,
    unsigned short* __restrict__ w2f, unsigned short* __restrict__ wof,
    float* __restrict__ bcat)
{
  int i = blockIdx.x * 256 + threadIdx.x;
  if (i < 356352) {                       // conv weights
    int e = i & 7, l = (i >> 3) & 63, ks = (i >> 9) % 12;
    int rest = i / 6144; int nt2 = rest & 1, t = rest >> 1;
    int k = ks * 16 + (l >> 5) * 8 + e;   // 0..191
    int n = nt2 * 32 + (l & 31);          // 0..63
    const float* w; int j;
    if (t < 3)       { w = w1; j = t; }
    else if (t < 6)  { w = w2; j = t - 3; }
    else if (t < 11) { w = w3; j = t - 6; }
    else if (t < 20) { w = w4; j = t - 11; }
    else             { w = w5; j = t - 20; }
    wtcf[i] = f2bf(w[(j * 192 + k) * 64 + n]);
    return;
  }
  i -= 356352;
  if (i < 30720) {                        // w1f
    int e = i & 7, l = (i >> 3) & 63, ks = (i >> 9) % 20, nt = i / 10240;
    int h = nt * 32 + (l & 31), k = ks * 16 + (l >> 5) * 8 + e;
    w1f[i] = (h < 80) ? f2bf(wa1[k * 80 + h]) : (unsigned short)0;
    return;
  }
  i -= 30720;
  if (i < 30720) {                        // w2f
    int e = i & 7, l = (i >> 3) & 63, ks = (i >> 9) % 6, nt = i / 3072;
    int f = nt * 32 + (l & 31), k = ks * 16 + (l >> 5) * 8 + e;
    w2f[i] = (k < 80) ? f2bf(wa2[k * 320 + f]) : (unsigned short)0;
    return;
  }
  i -= 30720;
  if (i < 102400) {                       // wof
    int e = i & 7, l = (i >> 3) & 63, ks = (i >> 9) % 20, nt = i / 10240;
    int g = nt * 32 + (l & 31), k = ks * 16 + (l >> 5) * 8 + e;
    wof[i] = f2bf(wo[k * 320 + g]);
    return;
  }
  i -= 102400;
  if (i < 320) {
    float v;
    if (i < 64)       v = b1[i];
    else if (i < 128) v = b2[i - 64];
    else if (i < 192) v = b3[i - 128];
    else if (i < 256) v = b4[i - 192];
    else              v = b5[i - 256];
    bcat[i] = v;
  }
}

// ---------------- conv: 5 causal dilated branches -> xc bf16 [M][320] -------
// 256 thr / 4 waves, M=64. Wave owns whole 32-col n-tiles (all taps, both
// 32-row halves) -> each weight fragment loaded exactly once per block,
// coalesced. Schedule: w0{8,4} w1{9,5} w2{6,0,2} w3{7,1,3} = 14/14/15/15 taps.
__global__ __launch_bounds__(256, 2) void k_conv(
    const float* __restrict__ x, const unsigned short* __restrict__ wtcf,
    const float* __restrict__ bcat, unsigned short* __restrict__ xc)
{
  __shared__ unsigned short xs[160 * 196];   // 62.7 KB
  int bid = blockIdx.x;
  bid = (bid & 7) * 256 + (bid >> 3);        // XCD swizzle (2048 % 8 == 0)
  const int m0 = bid * 64;
  const int b  = m0 >> 12;
  const int t0 = m0 & 4095;
  const int tid = threadIdx.x;

  const float* xb = x + (size_t)b * 4096 * 192;
  for (int c = tid; c < 160 * 48; c += 256) {
    int r = c / 48, f = c - r * 48;
    int tp = t0 - 96 + r;
    float4 v = make_float4(0.f, 0.f, 0.f, 0.f);
    if (tp >= 0) v = *(const float4*)(xb + (size_t)tp * 192 + f * 4);
    us4 o = { f2bf(v.x), f2bf(v.y), f2bf(v.z), f2bf(v.w) };
    *(us4*)(&xs[r * 196 + f * 4]) = o;
  }
  __syncthreads();

  const int wid = tid >> 6, lane = tid & 63;
  const int l31 = lane & 31, lh = lane >> 5;
  const int KT[5] = {3, 3, 5, 9, 9};
  const int DL[5] = {1, 2, 4, 8, 12};
  const int TB[5] = {0, 3, 6, 11, 20};
  const int SCHED[4][3] = {{8,4,-1},{9,5,-1},{6,0,2},{7,1,3}};

  #pragma unroll
  for (int slot = 0; slot < 3; ++slot) {
    const int t = SCHED[wid][slot];
    if (t < 0) continue;
    const int br = t >> 1;
    const int kt = KT[br], dl = DL[br], tb = TB[br];
    f32x16 acc0 = zero16(), acc1 = zero16();
    for (int j = 0; j < kt; ++j) {
      const int roff = 96 - dl * (kt - 1 - j);       // causal offset
      const unsigned short* wp =
          wtcf + (size_t)(((tb + j) * 2 + (t & 1)) * 12) * 512 + lane * 8;
      const unsigned short* xr0 = &xs[(roff + l31) * 196 + lh * 8];
      const unsigned short* xr1 = &xs[(roff + 32 + l31) * 196 + lh * 8];
      #pragma unroll
      for (int ks = 0; ks < 12; ++ks) {
        short8 bf = *(const short8*)(wp + ks * 512);
        short8 a0 = *(const short8*)(xr0 + ks * 16);
        short8 a1 = *(const short8*)(xr1 + ks * 16);
        acc0 = MFMA32(a0, bf, acc0);
        acc1 = MFMA32(a1, bf, acc1);
      }
    }
    const float bias = bcat[t * 32 + l31];
    unsigned short* dst = xc + (size_t)m0 * 320 + t * 32 + l31;
    #pragma unroll
    for (int r = 0; r < 16; ++r) {
      int row = (r & 3) + 8 * (r >> 2) + 4 * lh;
      float v0 = acc0[r] + bias; v0 = v0 > 0.f ? v0 : 0.f;
      float v1 = acc1[r] + bias; v1 = v1 > 0.f ? v1 : 0.f;
      dst[(size_t)row * 320]        = f2bf(v0);
      dst[(size_t)(row + 32) * 320] = f2bf(v1);
    }
  }
}

// ---------------- fused gate + out ------------------------------------------
// 640 thr / 10 waves, M=64. xc tile staged once in XOR-swizzled LDS; att1,
// att2 from frag-major global weights (no staging barriers); sigmoid applied
// in-LDS; out-GEMM from same LDS. 3 barriers total.
__global__ __launch_bounds__(640, 2) void k_gateout(
    const unsigned short* __restrict__ xc,
    const unsigned short* __restrict__ w1f, const unsigned short* __restrict__ w2f,
    const unsigned short* __restrict__ wof,
    const float* __restrict__ ba1, const float* __restrict__ ba2,
    const float* __restrict__ bo, float* __restrict__ out)
{
  __shared__ unsigned char xsb[64 * 640];   // 40 KB, XOR-swizzled rows (640 B)
  __shared__ unsigned char a1b[64 * 256];   // 16 KB, XOR-swizzled rows (256 B)
  int bid = blockIdx.x;
  bid = (bid & 7) * 256 + (bid >> 3);       // same swizzle as conv writer
  const int m0 = bid * 64;
  const int tid = threadIdx.x;
  const int wid = tid >> 6, lane = tid & 63;
  const int l31 = lane & 31, lh = lane >> 5;
  const int sw = (l31 & 7) << 4;            // row-XOR for rows == l31 (mod 8)

  // stage xc[m0..m0+63][0..319] -> swizzled LDS
  for (int i = tid; i < 64 * 40; i += 640) {
    int row = i / 40, cb = i % 40;
    short8 v = *(const short8*)(xc + (size_t)(m0 + row) * 320 + cb * 8);
    *(short8*)(xsb + row * 640 + ((cb * 16) ^ ((row & 7) << 4))) = v;
  }
  __syncthreads();

  // ph1: att1 = relu(xs @ W1 + b1) -> a1 (cols 80..95 pad to exact 0)
  if (wid < 6) {
    const int mt = wid / 3, nt1 = wid % 3;
    const int arow = mt * 32 + l31;
    f32x16 acc = zero16();
    const unsigned short* bp = w1f + (size_t)(nt1 * 20) * 512 + lane * 8;
    #pragma unroll
    for (int ks = 0; ks < 20; ++ks) {
      short8 af = *(const short8*)(xsb + arow * 640 + ((ks * 32 + lh * 16) ^ sw));
      short8 bf = *(const short8*)(bp + ks * 512);
      acc = MFMA32(af, bf, acc);
    }
    const int h = nt1 * 32 + l31;
    const float bias = (h < 80) ? ba1[h] : 0.f;
    #pragma unroll
    for (int r = 0; r < 16; ++r) {
      int row = mt * 32 + (r & 3) + 8 * (r >> 2) + 4 * lh;
      float v = acc[r] + bias;
      v = v > 0.f ? v : 0.f;
      *(unsigned short*)(a1b + row * 256 + ((2 * h) ^ ((row & 7) << 4))) = f2bf(v);
    }
  }
  __syncthreads();

  // ph2: att2 = sigmoid(a1 @ W2 + b2); ph3: xs *= att2 (in-LDS)
  const int mt2 = wid & 1, nst = wid >> 1;  // 2 x 5 strips of 32x64
  {
    const int arow = mt2 * 32 + l31;
    f32x16 acc2a = zero16(), acc2b = zero16();
    const unsigned short* bp0 = w2f + (size_t)((nst * 2 + 0) * 6) * 512 + lane * 8;
    const unsigned short* bp1 = w2f + (size_t)((nst * 2 + 1) * 6) * 512 + lane * 8;
    #pragma unroll
    for (int ks = 0; ks < 6; ++ks) {
      short8 af = *(const short8*)(a1b + arow * 256 + ((ks * 32 + lh * 16) ^ sw));
      short8 b0 = *(const short8*)(bp0 + ks * 512);
      short8 b1 = *(const short8*)(bp1 + ks * 512);
      acc2a = MFMA32(af, b0, acc2a);
      acc2b = MFMA32(af, b1, acc2b);
    }
    #pragma unroll
    for (int t = 0; t < 2; ++t) {
      const f32x16& a2 = t ? acc2b : acc2a;
      const int col = nst * 64 + t * 32 + l31;
      const float bias = ba2[col];
      #pragma unroll
      for (int r = 0; r < 16; ++r) {
        int row = mt2 * 32 + (r & 3) + 8 * (r >> 2) + 4 * lh;
        float v = a2[r] + bias;
        float s = 1.f / (1.f + __expf(-v));
        unsigned short* p =
            (unsigned short*)(xsb + row * 640 + ((2 * col) ^ ((row & 7) << 4)));
        *p = f2bf(bf2f(*p) * s);
      }
    }
  }
  __syncthreads();

  // ph4: out = xs(=xa) @ W_out + b_out
  {
    const int arow = mt2 * 32 + l31;
    f32x16 acc0 = zero16(), acc1 = zero16();
    const unsigned short* bp0 = wof + (size_t)((nst * 2 + 0) * 20) * 512 + lane * 8;
    const unsigned short* bp1 = wof + (size_t)((nst * 2 + 1) * 20) * 512 + lane * 8;
    #pragma unroll
    for (int ks = 0; ks < 20; ++ks) {
      short8 af = *(const short8*)(xsb + arow * 640 + ((ks * 32 + lh * 16) ^ sw));
      short8 b0 = *(const short8*)(bp0 + ks * 512);
      short8 b1 = *(const short8*)(bp1 + ks * 512);
      acc0 = MFMA32(af, b0, acc0);
      acc1 = MFMA32(af, b1, acc1);
    }
    #pragma unroll
    for (int t = 0; t < 2; ++t) {
      const f32x16& a = t ? acc1 : acc0;
      const int col = nst * 64 + t * 32 + l31;
      const float bias = bo[col];
      #pragma unroll
      for (int r = 0; r < 16; ++r) {
        int row = mt2 * 32 + (r & 3) + 8 * (r >> 2) + 4 * lh;
        out[(size_t)(m0 + row) * 320 + col] = a[r] + bias;
      }
    }
  }
}

// ---------------- host ------------------------------------------------------
extern "C" void kernel_launch(void* const* d_in, const int* in_sizes, int n_in,
                              void* d_out, int out_size, void* d_ws, size_t ws_size,
                              hipStream_t stream) {
  const float* x    = (const float*)d_in[0];
  const float* w_b1 = (const float*)d_in[1];  const float* b_b1 = (const float*)d_in[2];
  const float* w_b2 = (const float*)d_in[3];  const float* b_b2 = (const float*)d_in[4];
  const float* w_b3 = (const float*)d_in[5];  const float* b_b3 = (const float*)d_in[6];
  const float* w_b4 = (const float*)d_in[7];  const float* b_b4 = (const float*)d_in[8];
  const float* w_b5 = (const float*)d_in[9];  const float* b_b5 = (const float*)d_in[10];
  const float* wa1  = (const float*)d_in[11]; const float* ba1  = (const float*)d_in[12];
  const float* wa2  = (const float*)d_in[13]; const float* ba2  = (const float*)d_in[14];
  const float* wo   = (const float*)d_in[15]; const float* bo   = (const float*)d_in[16];

  char* ws = (char*)d_ws;
  unsigned short* xc   = (unsigned short*)(ws);              // 83,886,080 B
  unsigned short* wtcf = (unsigned short*)(ws + 83886080);   // 712,704
  unsigned short* w1f  = (unsigned short*)(ws + 84598784);   // 61,440
  unsigned short* w2f  = (unsigned short*)(ws + 84660224);   // 61,440
  unsigned short* wof  = (unsigned short*)(ws + 84721664);   // 204,800
  float*          bct  = (float*)         (ws + 84926464);   // 1,280

  k_prep<<<2034, 256, 0, stream>>>(w_b1, w_b2, w_b3, w_b4, w_b5,
                                   b_b1, b_b2, b_b3, b_b4, b_b5,
                                   wa1, wa2, wo, wtcf, w1f, w2f, wof, bct);
  k_conv<<<2048, 256, 0, stream>>>(x, wtcf, bct, xc);
  k_gateout<<<2048, 640, 0, stream>>>(xc, w1f, w2f, wof, ba1, ba2, bo,
                                      (float*)d_out);
}

// Round 5
// 576.839 us; speedup vs baseline: 1.2317x; 1.2317x over previous
//
#include <hip/hip_runtime.h>

typedef __attribute__((ext_vector_type(8))) short short8;
typedef __attribute__((ext_vector_type(16))) float f32x16;
typedef __attribute__((ext_vector_type(4))) unsigned short us4;

#define MFMA32(a,b,c) __builtin_amdgcn_mfma_f32_32x32x16_bf16((a),(b),(c),0,0,0)

__device__ __forceinline__ unsigned short f2bf(float f) {
  union { float f; unsigned u; } v; v.f = f;
  return (unsigned short)((v.u + 0x7fffu + ((v.u >> 16) & 1u)) >> 16);
}
__device__ __forceinline__ float bf2f(unsigned short h) {
  union { unsigned u; float f; } v; v.u = ((unsigned)h) << 16;
  return v.f;
}
__device__ __forceinline__ f32x16 zero16() {
  f32x16 v;
  #pragma unroll
  for (int i = 0; i < 16; ++i) v[i] = 0.f;
  return v;
}

// ---------------- prep: weights -> bf16 fragment-major layouts --------------
//   frag[unit][ks][lane*8+e] = W[k = ks*16 + (lane>>5)*8 + e][col = base + (lane&31)]
// wtcf: [29 taps][2 nhalf][12 ks][512]   (conv, K=192)
// w1f : [3 nt][20 ks][512]  cols 80..95 zero-padded (att1, K=320)
// w2f : [10 nt][6 ks][512]  k 80..95 zero-padded    (att2, K=96)
// wof : [10 nt][20 ks][512]                          (out,  K=320)
__global__ __launch_bounds__(256) void k_prep(
    const float* __restrict__ w1, const float* __restrict__ w2,
    const float* __restrict__ w3, const float* __restrict__ w4,
    const float* __restrict__ w5,
    const float* __restrict__ b1, const float* __restrict__ b2,
    const float* __restrict__ b3, const float* __restrict__ b4,
    const float* __restrict__ b5,
    const float* __restrict__ wa1, const float* __restrict__ wa2,
    const float* __restrict__ wo,
    unsigned short* __restrict__ wtcf, unsigned short* __restrict__ w1f,
    unsigned short* __restrict__ w2f, unsigned short* __restrict__ wof,
    float* __restrict__ bcat)
{
  int i = blockIdx.x * 256 + threadIdx.x;
  if (i < 356352) {                       // conv weights
    int e = i & 7, l = (i >> 3) & 63, ks = (i >> 9) % 12;
    int rest = i / 6144; int nt2 = rest & 1, t = rest >> 1;
    int k = ks * 16 + (l >> 5) * 8 + e;   // 0..191
    int n = nt2 * 32 + (l & 31);          // 0..63
    const float* w; int j;
    if (t < 3)       { w = w1; j = t; }
    else if (t < 6)  { w = w2; j = t - 3; }
    else if (t < 11) { w = w3; j = t - 6; }
    else if (t < 20) { w = w4; j = t - 11; }
    else             { w = w5; j = t - 20; }
    wtcf[i] = f2bf(w[(j * 192 + k) * 64 + n]);
    return;
  }
  i -= 356352;
  if (i < 30720) {                        // w1f
    int e = i & 7, l = (i >> 3) & 63, ks = (i >> 9) % 20, nt = i / 10240;
    int h = nt * 32 + (l & 31), k = ks * 16 + (l >> 5) * 8 + e;
    w1f[i] = (h < 80) ? f2bf(wa1[k * 80 + h]) : (unsigned short)0;
    return;
  }
  i -= 30720;
  if (i < 30720) {                        // w2f
    int e = i & 7, l = (i >> 3) & 63, ks = (i >> 9) % 6, nt = i / 3072;
    int f = nt * 32 + (l & 31), k = ks * 16 + (l >> 5) * 8 + e;
    w2f[i] = (k < 80) ? f2bf(wa2[k * 320 + f]) : (unsigned short)0;
    return;
  }
  i -= 30720;
  if (i < 102400) {                       // wof
    int e = i & 7, l = (i >> 3) & 63, ks = (i >> 9) % 20, nt = i / 10240;
    int g = nt * 32 + (l & 31), k = ks * 16 + (l >> 5) * 8 + e;
    wof[i] = f2bf(wo[k * 320 + g]);
    return;
  }
  i -= 102400;
  if (i < 320) {
    float v;
    if (i < 64)       v = b1[i];
    else if (i < 128) v = b2[i - 64];
    else if (i < 192) v = b3[i - 128];
    else if (i < 256) v = b4[i - 192];
    else              v = b5[i - 256];
    bcat[i] = v;
  }
}

// ---------------- fused conv -> gate -> out ---------------------------------
// One block = 64 output rows. LDS: xs (x window, 160 rows x 400B) reused as
// a1b after conv; xcb (xc tile, 64 x 640B XOR-swizzled chunks).
#define XS_STRIDE 400        // bytes per xs row (200 shorts, 16B-aligned)
#define XCB_OFF   64000
#define LDS_TOTAL (64000 + 40960)

// conv unit: one branch, one 32-row m-tile, both 32-col n-halves.
// Fully unrolled (compile-time KT) so weight loads pipeline deeply.
template<int KT, int DL, int TB>
__device__ __forceinline__ void conv_unit(
    const unsigned char* __restrict__ smem,
    unsigned char* __restrict__ xcb,
    const unsigned short* __restrict__ wtcf,
    const float* __restrict__ bcat,
    int br, int mt, int l31, int lh, int lane)
{
  f32x16 a0e = zero16(), a0o = zero16(), a1e = zero16(), a1o = zero16();
  const int arow0 = 96 + mt * 32 + l31;
  #pragma unroll
  for (int j = 0; j < KT; ++j) {
    const int roff = arow0 - DL * (KT - 1 - j);
    const unsigned char* xr = smem + roff * XS_STRIDE + lh * 16;
    const unsigned short* wp0 = wtcf + (size_t)((TB + j) * 2 + 0) * 6144 + lane * 8;
    const unsigned short* wp1 = wp0 + 6144;
    #pragma unroll
    for (int ks = 0; ks < 12; ks += 2) {
      short8 be0 = *(const short8*)(wp0 + ks * 512);
      short8 be1 = *(const short8*)(wp1 + ks * 512);
      short8 ae  = *(const short8*)(xr + ks * 32);
      a0e = MFMA32(ae, be0, a0e);
      a1e = MFMA32(ae, be1, a1e);
      short8 bo0 = *(const short8*)(wp0 + ks * 512 + 512);
      short8 bo1 = *(const short8*)(wp1 + ks * 512 + 512);
      short8 ao  = *(const short8*)(xr + ks * 32 + 32);
      a0o = MFMA32(ao, bo0, a0o);
      a1o = MFMA32(ao, bo1, a1o);
    }
  }
  #pragma unroll
  for (int nh = 0; nh < 2; ++nh) {
    const int col = (br * 2 + nh) * 32 + l31;
    const float bias = bcat[col];
    #pragma unroll
    for (int r = 0; r < 16; ++r) {
      int row = mt * 32 + (r & 3) + 8 * (r >> 2) + 4 * lh;
      float v = (nh ? (a1e[r] + a1o[r]) : (a0e[r] + a0o[r])) + bias;
      v = v > 0.f ? v : 0.f;
      *(unsigned short*)(xcb + row * 640 + ((2 * col) ^ ((row & 7) << 4))) = f2bf(v);
    }
  }
}

__global__ __launch_bounds__(512, 2) void k_fused(
    const float* __restrict__ x, const unsigned short* __restrict__ wtcf,
    const unsigned short* __restrict__ w1f, const unsigned short* __restrict__ w2f,
    const unsigned short* __restrict__ wof, const float* __restrict__ bcat,
    const float* __restrict__ ba1, const float* __restrict__ ba2,
    const float* __restrict__ bo, float* __restrict__ out)
{
  __shared__ __align__(16) unsigned char smem[LDS_TOTAL];
  unsigned char* xcb = smem + XCB_OFF;   // [64 rows][640 B], chunk-XOR swizzle
  unsigned char* a1b = smem;             // overlays xs after conv phase

  int bid = blockIdx.x;
  bid = (bid & 7) * 256 + (bid >> 3);    // XCD swizzle (2048 % 8 == 0)
  const int m0 = bid * 64;
  const int b  = m0 >> 12;
  const int t0 = m0 & 4095;
  const int tid = threadIdx.x;
  const int wid = tid >> 6, lane = tid & 63;
  const int l31 = lane & 31, lh = lane >> 5;
  const int sw = (l31 & 7) << 4;

  // ---- stage x window: rows [t0-96, t0+64) x 192ch -> bf16 LDS ----
  const float* xb = x + (size_t)b * 4096 * 192;
  #pragma unroll
  for (int it = 0; it < 15; ++it) {
    int c = tid + it * 512;              // 7680 = 160 rows x 48 float4
    int r = c / 48, f = c - r * 48;
    int tp = t0 - 96 + r;
    float4 v = make_float4(0.f, 0.f, 0.f, 0.f);
    if (tp >= 0) v = *(const float4*)(xb + (size_t)tp * 192 + f * 4);
    us4 o = { f2bf(v.x), f2bf(v.y), f2bf(v.z), f2bf(v.w) };
    *(us4*)(smem + r * XS_STRIDE + f * 8) = o;
  }
  __syncthreads();

  // ---- conv: waves 0-7 = (br4,m0)(br4,m1)(br3,m0)(br3,m1)(br2,m0)(br2,m1)
  //                        (br1+br0,m0)(br1+br0,m1) ----
  {
    const int mt = wid & 1;
    switch (wid >> 1) {
      case 0: conv_unit<9,12,20>(smem, xcb, wtcf, bcat, 4, mt, l31, lh, lane); break;
      case 1: conv_unit<9, 8,11>(smem, xcb, wtcf, bcat, 3, mt, l31, lh, lane); break;
      case 2: conv_unit<5, 4, 6>(smem, xcb, wtcf, bcat, 2, mt, l31, lh, lane); break;
      default:
        conv_unit<3, 2, 3>(smem, xcb, wtcf, bcat, 1, mt, l31, lh, lane);
        conv_unit<3, 1, 0>(smem, xcb, wtcf, bcat, 0, mt, l31, lh, lane);
        break;
    }
  }
  __syncthreads();

  // ---- ph1: att1 = relu(xc @ W1 + b1) -> a1b (waves 0-5) ----
  if (wid < 6) {
    const int mt = wid & 1, nt1 = wid >> 1;
    const int arow = mt * 32 + l31;
    f32x16 acc = zero16();
    const unsigned short* bp = w1f + (size_t)(nt1 * 20) * 512 + lane * 8;
    #pragma unroll
    for (int ks = 0; ks < 20; ++ks) {
      short8 af = *(const short8*)(xcb + arow * 640 + ((ks * 32 + lh * 16) ^ sw));
      short8 bf = *(const short8*)(bp + ks * 512);
      acc = MFMA32(af, bf, acc);
    }
    const int h = nt1 * 32 + l31;
    const float bias = (h < 80) ? ba1[h] : 0.f;
    #pragma unroll
    for (int r = 0; r < 16; ++r) {
      int row = mt * 32 + (r & 3) + 8 * (r >> 2) + 4 * lh;
      float v = acc[r] + bias;
      v = v > 0.f ? v : 0.f;
      *(unsigned short*)(a1b + row * 256 + ((2 * h) ^ ((row & 7) << 4))) = f2bf(v);
    }
  }
  __syncthreads();

  // ---- ph2: att2 = sigmoid(a1 @ W2 + b2); xcb *= att2 ----
  const int mt2 = wid & 1, g = wid >> 1;
  const int tcount = (g < 2) ? 3 : 2;
  const int tbase  = (g < 2) ? g * 3 : 6 + (g - 2) * 2;
  const int arow2 = mt2 * 32 + l31;
  {
    f32x16 acc2[3];
    #pragma unroll
    for (int t = 0; t < 3; ++t) acc2[t] = zero16();
    #pragma unroll
    for (int ks = 0; ks < 6; ++ks) {
      short8 af = *(const short8*)(a1b + arow2 * 256 + ((ks * 32 + lh * 16) ^ sw));
      #pragma unroll
      for (int t = 0; t < 3; ++t) if (t < tcount) {
        short8 bf = *(const short8*)(w2f + (size_t)((tbase + t) * 6 + ks) * 512 + lane * 8);
        acc2[t] = MFMA32(af, bf, acc2[t]);
      }
    }
    #pragma unroll
    for (int t = 0; t < 3; ++t) if (t < tcount) {
      const int col = (tbase + t) * 32 + l31;
      const float bias = ba2[col];
      #pragma unroll
      for (int r = 0; r < 16; ++r) {
        int row = mt2 * 32 + (r & 3) + 8 * (r >> 2) + 4 * lh;
        float v = acc2[t][r] + bias;
        float s = 1.f / (1.f + __expf(-v));
        unsigned short* p =
            (unsigned short*)(xcb + row * 640 + ((2 * col) ^ ((row & 7) << 4)));
        *p = f2bf(bf2f(*p) * s);
      }
    }
  }
  __syncthreads();

  // ---- ph4: out = xa @ W_out + b_out ----
  {
    f32x16 acc4[3];
    #pragma unroll
    for (int t = 0; t < 3; ++t) acc4[t] = zero16();
    #pragma unroll
    for (int ks = 0; ks < 20; ++ks) {
      short8 af = *(const short8*)(xcb + arow2 * 640 + ((ks * 32 + lh * 16) ^ sw));
      #pragma unroll
      for (int t = 0; t < 3; ++t) if (t < tcount) {
        short8 bf = *(const short8*)(wof + (size_t)((tbase + t) * 20 + ks) * 512 + lane * 8);
        acc4[t] = MFMA32(af, bf, acc4[t]);
      }
    }
    #pragma unroll
    for (int t = 0; t < 3; ++t) if (t < tcount) {
      const int col = (tbase + t) * 32 + l31;
      const float bias = bo[col];
      #pragma unroll
      for (int r = 0; r < 16; ++r) {
        int row = mt2 * 32 + (r & 3) + 8 * (r >> 2) + 4 * lh;
        out[(size_t)(m0 + row) * 320 + col] = acc4[t][r] + bias;
      }
    }
  }
}

// ---------------- host ------------------------------------------------------
extern "C" void kernel_launch(void* const* d_in, const int* in_sizes, int n_in,
                              void* d_out, int out_size, void* d_ws, size_t ws_size,
                              hipStream_t stream) {
  const float* x    = (const float*)d_in[0];
  const float* w_b1 = (const float*)d_in[1];  const float* b_b1 = (const float*)d_in[2];
  const float* w_b2 = (const float*)d_in[3];  const float* b_b2 = (const float*)d_in[4];
  const float* w_b3 = (const float*)d_in[5];  const float* b_b3 = (const float*)d_in[6];
  const float* w_b4 = (const float*)d_in[7];  const float* b_b4 = (const float*)d_in[8];
  const float* w_b5 = (const float*)d_in[9];  const float* b_b5 = (const float*)d_in[10];
  const float* wa1  = (const float*)d_in[11]; const float* ba1  = (const float*)d_in[12];
  const float* wa2  = (const float*)d_in[13]; const float* ba2  = (const float*)d_in[14];
  const float* wo   = (const float*)d_in[15]; const float* bo   = (const float*)d_in[16];

  char* ws = (char*)d_ws;
  unsigned short* wtcf = (unsigned short*)(ws);             // 712,704 B
  unsigned short* w1f  = (unsigned short*)(ws + 712704);    // 61,440
  unsigned short* w2f  = (unsigned short*)(ws + 774144);    // 61,440
  unsigned short* wof  = (unsigned short*)(ws + 835584);    // 204,800
  float*          bct  = (float*)         (ws + 1040384);   // 1,280

  k_prep<<<2034, 256, 0, stream>>>(w_b1, w_b2, w_b3, w_b4, w_b5,
                                   b_b1, b_b2, b_b3, b_b4, b_b5,
                                   wa1, wa2, wo, wtcf, w1f, w2f, wof, bct);
  k_fused<<<2048, 512, 0, stream>>>(x, wtcf, w1f, w2f, wof, bct,
                                    ba1, ba2, bo, (float*)d_out);
}

// Round 6
// 492.904 us; speedup vs baseline: 1.4415x; 1.1703x over previous
//
#include <hip/hip_runtime.h>

typedef __attribute__((ext_vector_type(8))) short short8;
typedef __attribute__((ext_vector_type(16))) float f32x16;
typedef __attribute__((ext_vector_type(4))) unsigned short us4;

#define MFMA32(a,b,c) __builtin_amdgcn_mfma_f32_32x32x16_bf16((a),(b),(c),0,0,0)

__device__ __forceinline__ unsigned short f2bf(float f) {
  union { float f; unsigned u; } v; v.f = f;
  return (unsigned short)((v.u + 0x7fffu + ((v.u >> 16) & 1u)) >> 16);
}
__device__ __forceinline__ float bf2f(unsigned short h) {
  union { unsigned u; float f; } v; v.u = ((unsigned)h) << 16;
  return v.f;
}
__device__ __forceinline__ f32x16 zero16() {
  f32x16 v;
  #pragma unroll
  for (int i = 0; i < 16; ++i) v[i] = 0.f;
  return v;
}
__device__ __forceinline__ void gload16(const void* g, void* l) {
  __builtin_amdgcn_global_load_lds(
      (const __attribute__((address_space(1))) void*)(g),
      (__attribute__((address_space(3))) void*)(l), 16, 0, 0);
}

// ---------------- prep: weights -> bf16 fragment-major layouts --------------
//   frag[unit][ks][lane*8+e] = W[k = ks*16 + (lane>>5)*8 + e][col = base + (lane&31)]
// wtcf: [29 taps][2 nhalf][12 ks][512]   (conv, K=192)
// w1f : [3 nt][20 ks][512]  cols 80..95 zero-padded (att1, K=320)
// w2f : [10 nt][6 ks][512]  k 80..95 zero-padded    (att2, K=96)
// wof : [10 nt][20 ks][512]                          (out,  K=320)
__global__ __launch_bounds__(256) void k_prep(
    const float* __restrict__ w1, const float* __restrict__ w2,
    const float* __restrict__ w3, const float* __restrict__ w4,
    const float* __restrict__ w5,
    const float* __restrict__ b1, const float* __restrict__ b2,
    const float* __restrict__ b3, const float* __restrict__ b4,
    const float* __restrict__ b5,
    const float* __restrict__ wa1, const float* __restrict__ wa2,
    const float* __restrict__ wo,
    unsigned short* __restrict__ wtcf, unsigned short* __restrict__ w1f,
    unsigned short* __restrict__ w2f, unsigned short* __restrict__ wof,
    float* __restrict__ bcat)
{
  int i = blockIdx.x * 256 + threadIdx.x;
  if (i < 356352) {                       // conv weights
    int e = i & 7, l = (i >> 3) & 63, ks = (i >> 9) % 12;
    int rest = i / 6144; int nt2 = rest & 1, t = rest >> 1;
    int k = ks * 16 + (l >> 5) * 8 + e;   // 0..191
    int n = nt2 * 32 + (l & 31);          // 0..63
    const float* w; int j;
    if (t < 3)       { w = w1; j = t; }
    else if (t < 6)  { w = w2; j = t - 3; }
    else if (t < 11) { w = w3; j = t - 6; }
    else if (t < 20) { w = w4; j = t - 11; }
    else             { w = w5; j = t - 20; }
    wtcf[i] = f2bf(w[(j * 192 + k) * 64 + n]);
    return;
  }
  i -= 356352;
  if (i < 30720) {                        // w1f
    int e = i & 7, l = (i >> 3) & 63, ks = (i >> 9) % 20, nt = i / 10240;
    int h = nt * 32 + (l & 31), k = ks * 16 + (l >> 5) * 8 + e;
    w1f[i] = (h < 80) ? f2bf(wa1[k * 80 + h]) : (unsigned short)0;
    return;
  }
  i -= 30720;
  if (i < 30720) {                        // w2f
    int e = i & 7, l = (i >> 3) & 63, ks = (i >> 9) % 6, nt = i / 3072;
    int f = nt * 32 + (l & 31), k = ks * 16 + (l >> 5) * 8 + e;
    w2f[i] = (k < 80) ? f2bf(wa2[k * 320 + f]) : (unsigned short)0;
    return;
  }
  i -= 30720;
  if (i < 102400) {                       // wof
    int e = i & 7, l = (i >> 3) & 63, ks = (i >> 9) % 20, nt = i / 10240;
    int g = nt * 32 + (l & 31), k = ks * 16 + (l >> 5) * 8 + e;
    wof[i] = f2bf(wo[k * 320 + g]);
    return;
  }
  i -= 102400;
  if (i < 320) {
    float v;
    if (i < 64)       v = b1[i];
    else if (i < 128) v = b2[i - 64];
    else if (i < 192) v = b3[i - 128];
    else if (i < 256) v = b4[i - 192];
    else              v = b5[i - 256];
    bcat[i] = v;
  }
}

// ---------------- conv: M=128, 16 waves, writes swizzled xc into d_out ------
// LDS: x window, 224 rows x 512B, byte col c' = c ^ ((row&15)<<4) (even-bank).
// xc global row = 768B, col byte c' = (2*col) ^ ((row&15)<<4).
template<int KT, int DL, int TB>
__device__ __forceinline__ void conv_unit(
    const unsigned char* smem, const unsigned short* __restrict__ wtcf,
    const float* __restrict__ bcat, unsigned char* __restrict__ xcg,
    int nh, int p, int br, int l31, int lh, int lane)
{
  f32x16 acc0 = zero16(), acc1 = zero16();
  const int r0 = 96 + p * 64 + l31;
  #pragma unroll
  for (int j = 0; j < KT; ++j) {
    const int row = r0 - DL * (KT - 1 - j);
    const int sw = (row & 15) << 4;            // same for row and row+32
    const unsigned char* x0 = smem + row * 512;
    const unsigned short* wp =
        wtcf + (size_t)(((TB + j) * 2 + nh) * 12) * 512 + lane * 8;
    #pragma unroll
    for (int ks = 0; ks < 12; ++ks) {
      const int cb = (ks * 32 + lh * 16) ^ sw;
      short8 bf = *(const short8*)(wp + ks * 512);
      short8 a0 = *(const short8*)(x0 + cb);
      short8 a1 = *(const short8*)(x0 + 32 * 512 + cb);
      acc0 = MFMA32(a0, bf, acc0);
      acc1 = MFMA32(a1, bf, acc1);
    }
  }
  const int col = (br * 2 + nh) * 32 + l31;
  const float bias = bcat[col];
  #pragma unroll
  for (int h = 0; h < 2; ++h) {
    const f32x16& A = h ? acc1 : acc0;
    #pragma unroll
    for (int r = 0; r < 16; ++r) {
      int row = p * 64 + h * 32 + (r & 3) + 8 * (r >> 2) + 4 * lh;
      float v = A[r] + bias; v = v > 0.f ? v : 0.f;
      *(unsigned short*)(xcg + (size_t)row * 768 +
                         ((2 * col) ^ ((row & 15) << 4))) = f2bf(v);
    }
  }
}

__global__ __launch_bounds__(1024, 4) void k_fconv(
    const float* __restrict__ x, const unsigned short* __restrict__ wtcf,
    const float* __restrict__ bcat, unsigned char* __restrict__ xcglob)
{
  __shared__ __align__(16) unsigned char smem[224 * 512];
  int bid = blockIdx.x;
  bid = (bid & 7) * 128 + (bid >> 3);          // XCD swizzle (1024 % 8 == 0)
  const int m0 = bid * 128;
  const int b  = m0 >> 12;
  const int t0 = m0 & 4095;
  const int tid = threadIdx.x;

  // stage x rows [t0-96, t0+128) x 192ch, fp32 -> bf16, swizzled
  const float* xb = x + (size_t)b * 4096 * 192;
  #pragma unroll
  for (int it = 0; it < 11; ++it) {
    int c = tid + it * 1024;                   // 10752 = 224 rows x 48 float4
    if (c < 10752) {
      int r = c / 48, f = c - r * 48;
      int tp = t0 - 96 + r;
      float4 v = make_float4(0.f, 0.f, 0.f, 0.f);
      if (tp >= 0) v = *(const float4*)(xb + (size_t)tp * 192 + f * 4);
      us4 o = { f2bf(v.x), f2bf(v.y), f2bf(v.z), f2bf(v.w) };
      *(us4*)(smem + r * 512 + ((f * 8) ^ ((r & 15) << 4))) = o;
    }
  }
  __syncthreads();

  const int wid = tid >> 6, lane = tid & 63;
  const int l31 = lane & 31, lh = lane >> 5;
  unsigned char* xcg = xcglob + (size_t)m0 * 1280;   // own slice of out buffer

  // waves: br3 x4, br4 x4, br2 x4, br0 x2(both p), br1 x2(both p)
  if (wid < 4)       conv_unit<9, 8,11>(smem, wtcf, bcat, xcg, (wid>>1)&1, wid&1, 3, l31, lh, lane);
  else if (wid < 8)  conv_unit<9,12,20>(smem, wtcf, bcat, xcg, (wid>>1)&1, wid&1, 4, l31, lh, lane);
  else if (wid < 12) conv_unit<5, 4, 6>(smem, wtcf, bcat, xcg, (wid>>1)&1, wid&1, 2, l31, lh, lane);
  else if (wid < 14) {
    conv_unit<3, 1, 0>(smem, wtcf, bcat, xcg, wid & 1, 0, 0, l31, lh, lane);
    conv_unit<3, 1, 0>(smem, wtcf, bcat, xcg, wid & 1, 1, 0, l31, lh, lane);
  } else {
    conv_unit<3, 2, 3>(smem, wtcf, bcat, xcg, wid & 1, 0, 1, l31, lh, lane);
    conv_unit<3, 2, 3>(smem, wtcf, bcat, xcg, wid & 1, 1, 1, l31, lh, lane);
  }
}

// ---------------- gate + out: M=128, 16 waves ------------------------------
__global__ __launch_bounds__(1024, 4) void k_gateout(
    const unsigned char* __restrict__ xcglob,
    const unsigned short* __restrict__ w1f, const unsigned short* __restrict__ w2f,
    const unsigned short* __restrict__ wof,
    const float* __restrict__ ba1, const float* __restrict__ ba2,
    const float* __restrict__ bo, float* __restrict__ out)
{
  __shared__ __align__(16) unsigned char smem[128 * 768 + 128 * 256];
  unsigned char* a1b = smem + 128 * 768;
  int bid = blockIdx.x;
  bid = (bid & 7) * 128 + (bid >> 3);
  const int m0 = bid * 128;
  const int tid = threadIdx.x;
  const int wid = tid >> 6, lane = tid & 63;
  const int l31 = lane & 31, lh = lane >> 5;
  const int sw15 = (l31 & 15) << 4, sw7 = (l31 & 7) << 4;

  // stage this block's xc tile (98304 B, linear copy of pre-swizzled rows)
  {
    const unsigned char* src = xcglob + (size_t)m0 * 1280 + wid * 6144 + lane * 16;
    unsigned char* dst = smem + wid * 6144;
    #pragma unroll
    for (int k = 0; k < 6; ++k)
      gload16(src + k * 1024, dst + k * 1024);
  }
  __syncthreads();

  // ph1: att1 = relu(xc @ W1 + b1) -> a1b (12 waves, (nt, mt) units)
  if (wid < 12) {
    const int nt = wid >> 2, mt = wid & 3;
    f32x16 acc = zero16();
    const unsigned short* bp = w1f + (size_t)(nt * 20) * 512 + lane * 8;
    const unsigned char* ar = smem + (size_t)(mt * 32 + l31) * 768;
    #pragma unroll
    for (int ks = 0; ks < 20; ++ks) {
      short8 af = *(const short8*)(ar + ((ks * 32 + lh * 16) ^ sw15));
      short8 bf = *(const short8*)(bp + ks * 512);
      acc = MFMA32(af, bf, acc);
    }
    const int h = nt * 32 + l31;
    const float bias = (h < 80) ? ba1[h] : 0.f;
    #pragma unroll
    for (int r = 0; r < 16; ++r) {
      int row = mt * 32 + (r & 3) + 8 * (r >> 2) + 4 * lh;
      float v = acc[r] + bias; v = v > 0.f ? v : 0.f;
      *(unsigned short*)(a1b + row * 256 + ((2 * h) ^ ((row & 7) << 4))) = f2bf(v);
    }
  }
  __syncthreads();

  // ph2: att2 = sigmoid(a1 @ W2 + b2); xc *= att2 in-LDS ((col,mt) units)
  for (int u = wid; u < 40; u += 16) {
    const int col = u >> 2, mt = u & 3;
    f32x16 acc = zero16();
    const unsigned char* ar = a1b + (size_t)(mt * 32 + l31) * 256;
    #pragma unroll
    for (int ks = 0; ks < 6; ++ks) {
      short8 af = *(const short8*)(ar + ((ks * 32 + lh * 16) ^ sw7));
      short8 bf = *(const short8*)(w2f + (size_t)(col * 6 + ks) * 512 + lane * 8);
      acc = MFMA32(af, bf, acc);
    }
    const float bias = ba2[col * 32 + l31];
    #pragma unroll
    for (int r = 0; r < 16; ++r) {
      int row = mt * 32 + (r & 3) + 8 * (r >> 2) + 4 * lh;
      float v = acc[r] + bias;
      float s = 1.f / (1.f + __expf(-v));
      unsigned short* pp = (unsigned short*)(smem + (size_t)row * 768 +
          ((2 * (col * 32 + l31)) ^ ((row & 15) << 4)));
      *pp = f2bf(bf2f(*pp) * s);
    }
  }
  __syncthreads();

  // ph4: out = xa @ W_out + b_out  ((col, p) units, 2 m-tiles per unit)
  for (int u = wid; u < 20; u += 16) {
    const int col = u >> 1, p = u & 1;
    f32x16 acc0 = zero16(), acc1 = zero16();
    const unsigned char* ar0 = smem + (size_t)(p * 64 + l31) * 768;
    const unsigned char* ar1 = ar0 + 32 * 768;
    const unsigned short* bp = wof + (size_t)(col * 20) * 512 + lane * 8;
    #pragma unroll
    for (int ks = 0; ks < 20; ++ks) {
      const int cb = (ks * 32 + lh * 16) ^ sw15;
      short8 bf = *(const short8*)(bp + ks * 512);
      short8 a0 = *(const short8*)(ar0 + cb);
      short8 a1 = *(const short8*)(ar1 + cb);
      acc0 = MFMA32(a0, bf, acc0);
      acc1 = MFMA32(a1, bf, acc1);
    }
    const float bias = bo[col * 32 + l31];
    #pragma unroll
    for (int h = 0; h < 2; ++h) {
      const f32x16& A = h ? acc1 : acc0;
      #pragma unroll
      for (int r = 0; r < 16; ++r) {
        int row = p * 64 + h * 32 + (r & 3) + 8 * (r >> 2) + 4 * lh;
        out[(size_t)(m0 + row) * 320 + col * 32 + l31] = A[r] + bias;
      }
    }
  }
}

// ---------------- host ------------------------------------------------------
extern "C" void kernel_launch(void* const* d_in, const int* in_sizes, int n_in,
                              void* d_out, int out_size, void* d_ws, size_t ws_size,
                              hipStream_t stream) {
  const float* x    = (const float*)d_in[0];
  const float* w_b1 = (const float*)d_in[1];  const float* b_b1 = (const float*)d_in[2];
  const float* w_b2 = (const float*)d_in[3];  const float* b_b2 = (const float*)d_in[4];
  const float* w_b3 = (const float*)d_in[5];  const float* b_b3 = (const float*)d_in[6];
  const float* w_b4 = (const float*)d_in[7];  const float* b_b4 = (const float*)d_in[8];
  const float* w_b5 = (const float*)d_in[9];  const float* b_b5 = (const float*)d_in[10];
  const float* wa1  = (const float*)d_in[11]; const float* ba1  = (const float*)d_in[12];
  const float* wa2  = (const float*)d_in[13]; const float* ba2  = (const float*)d_in[14];
  const float* wo   = (const float*)d_in[15]; const float* bo   = (const float*)d_in[16];

  char* ws = (char*)d_ws;
  unsigned short* wtcf = (unsigned short*)(ws);             // 712,704 B
  unsigned short* w1f  = (unsigned short*)(ws + 712704);    // 61,440
  unsigned short* w2f  = (unsigned short*)(ws + 774144);    // 61,440
  unsigned short* wof  = (unsigned short*)(ws + 835584);    // 204,800
  float*          bct  = (float*)         (ws + 1040384);   // 1,280

  k_prep<<<2034, 256, 0, stream>>>(w_b1, w_b2, w_b3, w_b4, w_b5,
                                   b_b1, b_b2, b_b3, b_b4, b_b5,
                                   wa1, wa2, wo, wtcf, w1f, w2f, wof, bct);
  // xc parked inside each block's own 128-row slice of d_out (race-free)
  k_fconv<<<1024, 1024, 0, stream>>>(x, wtcf, bct, (unsigned char*)d_out);
  k_gateout<<<1024, 1024, 0, stream>>>((const unsigned char*)d_out,
                                       w1f, w2f, wof, ba1, ba2, bo,
                                       (float*)d_out);
}